// Round 1
// baseline (121.605 us; speedup 1.0000x reference)
//
#include <hip/hip_runtime.h>

// B = 4194304 rows, x is (B,4) fp32 row-major. Three 3->4->1 MLPs; output
// selected by sel = x[:,1] in {0,1,2}. Memory-bound: 80 MiB traffic, ~12.7us
// floor at 6.3 TB/s. Branchless: compute all three nets, cndmask-select.

__global__ __launch_bounds__(256) void Program_72902774882571_kernel(
    const float* __restrict__ x,
    const float* __restrict__ Ws1, const float* __restrict__ bs1,
    const float* __restrict__ Ws2, const float* __restrict__ bs2,
    const float* __restrict__ Wu1, const float* __restrict__ bu1,
    const float* __restrict__ Wu2, const float* __restrict__ bu2,
    const float* __restrict__ Wd1, const float* __restrict__ bd1,
    const float* __restrict__ Wd2, const float* __restrict__ bd2,
    float* __restrict__ out, int n)
{
    int i = blockIdx.x * blockDim.x + threadIdx.x;
    if (i >= n) return;

    // One float4 per row: 16 B/lane coalesced load (1 KiB per wave per inst).
    float4 xv = reinterpret_cast<const float4*>(x)[i];
    const float x0 = xv.x, x1 = xv.y, x2 = xv.z;  // x1 is also the selector

    // Tiny MLP: h = relu(x3 @ W1 + b1) ; out = sigmoid(h @ W2 + b2)
    // W1 is (3,4) row-major: W1[i][j] = W1[i*4+j]. W2 is (4,1).
    // Weight loads are wave-uniform kernel-arg addresses -> scalar s_loads.
    auto net = [&](const float* __restrict__ W1, const float* __restrict__ b1,
                   const float* __restrict__ W2, const float* __restrict__ b2) -> float {
        float acc = b2[0];
#pragma unroll
        for (int j = 0; j < 4; ++j) {
            float h = b1[j];
            h = fmaf(x0, W1[0 * 4 + j], h);
            h = fmaf(x1, W1[1 * 4 + j], h);
            h = fmaf(x2, W1[2 * 4 + j], h);
            h = fmaxf(h, 0.0f);          // relu
            acc = fmaf(h, W2[j], acc);
        }
        // sigmoid: 1/(1+exp(-acc)) ; v_exp_f32 is ~2ulp, threshold is 1e-2
        return 1.0f / (1.0f + __expf(-acc));
    };

    const float os = net(Ws1, bs1, Ws2, bs2);
    const float ou = net(Wu1, bu1, Wu2, bu2);
    const float od = net(Wd1, bd1, Wd2, bd2);

    // where(sel==0, s, where(sel==1, u, where(sel==2, d, 0)))
    float r = (x1 == 2.0f) ? od : 0.0f;
    r = (x1 == 1.0f) ? ou : r;
    r = (x1 == 0.0f) ? os : r;

    out[i] = r;  // 4 B/lane, 256 B/wave contiguous store
}

extern "C" void kernel_launch(void* const* d_in, const int* in_sizes, int n_in,
                              void* d_out, int out_size, void* d_ws, size_t ws_size,
                              hipStream_t stream) {
    const float* x   = (const float*)d_in[0];
    const float* Ws1 = (const float*)d_in[1];
    const float* bs1 = (const float*)d_in[2];
    const float* Ws2 = (const float*)d_in[3];
    const float* bs2 = (const float*)d_in[4];
    const float* Wu1 = (const float*)d_in[5];
    const float* bu1 = (const float*)d_in[6];
    const float* Wu2 = (const float*)d_in[7];
    const float* bu2 = (const float*)d_in[8];
    const float* Wd1 = (const float*)d_in[9];
    const float* bd1 = (const float*)d_in[10];
    const float* Wd2 = (const float*)d_in[11];
    const float* bd2 = (const float*)d_in[12];

    const int n = out_size;  // B = 4194304 rows
    const int block = 256;
    const int grid = (n + block - 1) / block;  // 16384 blocks

    Program_72902774882571_kernel<<<grid, block, 0, stream>>>(
        x, Ws1, bs1, Ws2, bs2, Wu1, bu1, Wu2, bu2, Wd1, bd1, Wd2, bd2,
        (float*)d_out, n);
}